// Round 3
// baseline (94.646 us; speedup 1.0000x reference)
//
#include <hip/hip_runtime.h>

#define NUM_K 64
#define CDIM 32
#define HW 16384          // 128*128
#define NPTS 1048576      // 64*128*128
#define NELEMD 33554432.0 // 64*32*128*128

// numpy pairwise sum, n=32, contiguous: 8 accumulators then fixed combine tree.
// a_i must already be the fp32-rounded products. NO contraction allowed here.
__device__ __forceinline__ float np_pairwise32(const float* a) {
#pragma clang fp contract(off)
    float r[8];
    #pragma unroll
    for (int j = 0; j < 8; ++j)
        r[j] = ((a[j] + a[j + 8]) + a[j + 16]) + a[j + 24];
    return ((r[0] + r[1]) + (r[2] + r[3])) + ((r[4] + r[5]) + (r[6] + r[7]));
}

__global__ __launch_bounds__(256) void vq_kernel(const float* __restrict__ x,
                                                 const float* __restrict__ emb,
                                                 float* __restrict__ outq,
                                                 double* __restrict__ ws) {
#pragma clang fp contract(off)
    __shared__ float sET[CDIM][NUM_K];  // transposed codebook for the divergent gather
    __shared__ float sB[NUM_K];         // np.sum(emb*emb, axis=1), numpy fp32 pairwise order
    __shared__ float sRed[4];

    const int t = threadIdx.x;
    for (int i = t; i < NUM_K * CDIM; i += 256) {
        sET[i & 31][i >> 5] = emb[i];
    }
    if (t < NUM_K) {
        const float* e = emb + t * CDIM;
        float bb[CDIM];
        #pragma unroll
        for (int c = 0; c < CDIM; ++c) { float v = e[c]; bb[c] = v * v; }  // plain mul, rounds
        sB[t] = np_pairwise32(bb);
    }
    __syncthreads();

    const int p = blockIdx.x * 256 + t;
    const int b = p >> 14;            // point / (128*128)
    const int rem = p & (HW - 1);
    const size_t base = (size_t)b * (CDIM * HW) + rem;
    const float* xp = x + base;

    float xv[CDIM];
    #pragma unroll
    for (int c = 0; c < CDIM; ++c) xv[c] = xp[(size_t)c * HW];  // coalesced across lanes

    // A = np.sum(x*x, axis=1) in numpy's exact fp32 order
    float aa[CDIM];
    #pragma unroll
    for (int c = 0; c < CDIM; ++c) aa[c] = xv[c] * xv[c];       // plain mul, rounds
    const float A = np_pairwise32(aa);

    // d_k = fp32( fp32(A + B_k) - 2*C_k ), C_k = ascending-k... ascending-c
    // sequential FMA chain (OpenBLAS sgemm microkernel rank-1-update model).
    // Ties on the ulp(~32) grid resolve to the FIRST k, matching np.argmin.
    float best = 3.4028235e38f;
    int bi = 0;
    #pragma unroll 4
    for (int k = 0; k < NUM_K; ++k) {
        const float* __restrict__ ek = emb + k * CDIM;  // uniform -> s_load
        float acc = 0.f;
        #pragma unroll
        for (int c = 0; c < CDIM; ++c)
            acc = fmaf(xv[c], ek[c], acc);              // single sequential FMA chain
        float t1 = A + sB[k];                           // fp32(A + B_k)
        float d  = t1 - (acc + acc);                    // (acc+acc) == 2C exactly
        if (d < best) { best = d; bi = k; }             // strict <: first-min
    }

    // ---- gather + store + loss partial
    float* op = outq + base;
    float lsum = 0.f;
    #pragma unroll
    for (int c = 0; c < CDIM; ++c) {
        float q = sET[c][bi];          // bank = bi%32 across lanes: ~free
        op[(size_t)c * HW] = q;        // coalesced across lanes
        float diff = q - xv[c];
        lsum = fmaf(diff, diff, lsum);
    }

    #pragma unroll
    for (int off = 32; off > 0; off >>= 1)
        lsum += __shfl_down(lsum, off, 64);
    const int wid = t >> 6;
    if ((t & 63) == 0) sRed[wid] = lsum;
    __syncthreads();
    if (t == 0) {
        double bs = (double)sRed[0] + (double)sRed[1] + (double)sRed[2] + (double)sRed[3];
        atomicAdd(ws, bs);   // f64 global atomic accumulator
    }
}

__global__ void vq_finish(const double* __restrict__ ws, float* __restrict__ loss) {
    loss[0] = (float)(1.25 * ws[0] / NELEMD);
}

extern "C" void kernel_launch(void* const* d_in, const int* in_sizes, int n_in,
                              void* d_out, int out_size, void* d_ws, size_t ws_size,
                              hipStream_t stream) {
    const float* x = (const float*)d_in[0];
    const float* emb = (const float*)d_in[1];
    float* out = (float*)d_out;
    double* ws = (double*)d_ws;

    hipMemsetAsync(d_ws, 0, sizeof(double), stream);  // atomic accumulator must start at 0 every call
    vq_kernel<<<NPTS / 256, 256, 0, stream>>>(x, emb, out + 1, ws);
    vq_finish<<<1, 1, 0, stream>>>(ws, out);
}